// Round 6
// baseline (503.935 us; speedup 1.0000x reference)
//
#include <hip/hip_runtime.h>

#define TT 128
#define BB 64
#define NIN 1024
#define NOUT 2048
#define MR (TT*BB)   // 8192 rows (T*B)

typedef unsigned short u16;
typedef __attribute__((ext_vector_type(8))) __bf16 bf16x8;
typedef __attribute__((ext_vector_type(4))) float f32x4;
typedef __attribute__((ext_vector_type(8))) unsigned short u16x8;

static __device__ __forceinline__ u16 f2bf(float f) {
    union { float f; unsigned u; } v; v.f = f;
    unsigned r = v.u + 0x7fffu + ((v.u >> 16) & 1u);  // RNE
    return (u16)(r >> 16);
}
static __device__ __forceinline__ float bf2f(u16 x) {
    union { unsigned u; float f; } v; v.u = ((unsigned)x) << 16;
    return v.f;
}

// ---- x [M][K] f32 -> chunked bf16 [(K/8)][M][8] ----
__global__ void k_cvt_chunk(const float* __restrict__ s, u16* __restrict__ d, int M_, int K_) {
    __shared__ float t[64][33];
    int m0 = blockIdx.x * 64, k0 = blockIdx.y * 32;
    int ml = threadIdx.x >> 3, kl = (threadIdx.x & 7) * 4;
    #pragma unroll
    for (int p = 0; p < 2; ++p) {
        float4 v = *(const float4*)&s[(size_t)(m0 + ml + p * 32) * K_ + k0 + kl];
        t[ml + p * 32][kl] = v.x; t[ml + p * 32][kl + 1] = v.y;
        t[ml + p * 32][kl + 2] = v.z; t[ml + p * 32][kl + 3] = v.w;
    }
    __syncthreads();
    int q = threadIdx.x >> 6, row = threadIdx.x & 63;
    u16x8 o;
    #pragma unroll
    for (int j = 0; j < 8; ++j) o[j] = f2bf(t[row][q * 8 + j]);
    *(u16x8*)&d[(((size_t)(k0 >> 3) + q) * M_ + m0 + row) * 8] = o;
}

// ---- W [K][N] f32 -> chunked bf16 B^T [(K/8)][OUTM][8] at row offset ----
__global__ void k_wT_chunk(const float* __restrict__ s, u16* __restrict__ d,
                           int K_, int N_, int OUTM, int row_off) {
    __shared__ float t[32][65];
    int k0 = blockIdx.y * 32, n0 = blockIdx.x * 64;
    int kl = threadIdx.x >> 6, nl = threadIdx.x & 63;
    #pragma unroll
    for (int p = 0; p < 8; ++p)
        t[kl + p * 4][nl] = s[(size_t)(k0 + kl + p * 4) * N_ + n0 + nl];
    __syncthreads();
    int q = threadIdx.x >> 6, row = threadIdx.x & 63;
    u16x8 o;
    #pragma unroll
    for (int j = 0; j < 8; ++j) o[j] = f2bf(t[q * 8 + j][row]);
    *(u16x8*)&d[(((size_t)(k0 >> 3) + q) * OUTM + row_off + n0 + row) * 8] = o;
}

__global__ void k_bias_pack(const float* __restrict__ bf_, const float* __restrict__ br_,
                            const float* __restrict__ bcx_, float* __restrict__ ball) {
    int i = blockIdx.x * 256 + threadIdx.x;
    int g = i >> 11, n = i & 2047;
    float v = 0.f;
    if (g == 1) v = bf_[n];
    else if (g == 2) v = br_[n];
    else if (g == 3) v = bcx_[n];
    ball[i] = v;
}

#define GLL16(SRC, DST) __builtin_amdgcn_global_load_lds( \
    (const __attribute__((address_space(1))) void*)(SRC), \
    (__attribute__((address_space(3))) void*)(DST), 16, 0, 0)
#define SBAR() __builtin_amdgcn_s_barrier()
#define SCHED0() __builtin_amdgcn_sched_barrier(0)
#define VM8 asm volatile("s_waitcnt vmcnt(8)" ::: "memory")
#define VM4 asm volatile("s_waitcnt vmcnt(4)" ::: "memory")
#define VM3 asm volatile("s_waitcnt vmcnt(3)" ::: "memory")
#define VM0 asm volatile("s_waitcnt vmcnt(0)" ::: "memory")

// ============ gate GEMM: BM=BN=256, BK=32, 8 waves, 4-deep ring, paced phases ============
// A [(K/8)][M][8], BT [(K/8)][NB][8] chunked bf16. Per K-tile: 2 barrier-paced phases,
// each MFMA cluster consumes frags read one full phase earlier (zero exposed lgkm);
// prefetch reads sit AFTER the vmcnt+barrier that publishes their tile (race-free).
__global__ __launch_bounds__(512, 2) void k_gemm8(
    const u16* __restrict__ A, const u16* __restrict__ BT,
    const float* __restrict__ bias, u16* __restrict__ outG,
    int M, int NB, int K)
{
    constexpr int BUF = 16384;               // elems per ring slot: A 8192 | B 8192
    __shared__ __align__(16) u16 L[4 * BUF]; // 128 KiB

    const int tid = threadIdx.x;
    const int w = tid >> 6, lane = tid & 63;
    const int wr = w >> 2, wc = w & 3;
    const int lr = lane & 15, kq = lane >> 4;
    // XCD column-band swizzle: xcd owns 4 contiguous n-tiles (2MB B slice, L2-fit)
    const int flat = blockIdx.y * gridDim.x + blockIdx.x;
    const int xcd = flat & 7, bi = flat >> 3;
    const int n0 = (xcd * 4 + (bi & 3)) * 256;
    const int m0 = (bi >> 2) * 256;
    const int nk = K >> 5;                   // BK = 32

    const int t1 = tid + 512;
    const u16* aS0 = A + ((size_t)(tid >> 8) * M + m0 + (tid & 255)) * 8;
    const u16* aS1 = A + ((size_t)(t1 >> 8) * M + m0 + (t1 & 255)) * 8;
    const u16* bS0 = BT + ((size_t)(tid >> 8) * NB + n0 + (tid & 255)) * 8;
    const u16* bS1 = BT + ((size_t)(t1 >> 8) * NB + n0 + (t1 & 255)) * 8;
    const int aD0 = (w * 64) * 8, aD1 = (512 + w * 64) * 8;
    const int bD0 = 8192 + aD0, bD1 = 8192 + aD1;
    const size_t aStep = (size_t)32 * M, bStep = (size_t)32 * NB;

    const int rA0 = (kq * 256 + wr * 128 + lr) * 8;        // aP rows 0-63 of wave tile
    const int rA1 = (kq * 256 + wr * 128 + 64 + lr) * 8;   // aG rows 64-127
    const int rB  = (kq * 256 + wc * 64 + lr) * 8;

    f32x4 acc[8][4] = {};
    bf16x8 aF0[4], aF1[4], bF0[4], bF1[4];

#define STAGE(TAU) { const size_t _oA = (size_t)(TAU) * aStep, _oB = (size_t)(TAU) * bStep; \
    const int _wb = ((TAU) & 3) * BUF; \
    GLL16(aS0 + _oA, &L[_wb + aD0]); GLL16(aS1 + _oA, &L[_wb + aD1]); \
    GLL16(bS0 + _oB, &L[_wb + bD0]); GLL16(bS1 + _oB, &L[_wb + bD1]); }
#define LDAP(DST, BB_) { _Pragma("unroll") for (int i = 0; i < 4; ++i) \
    DST[i] = *(const bf16x8*)&L[(BB_) + rA0 + i * 128]; }
#define LDAG(DST, BB_) { _Pragma("unroll") for (int i = 0; i < 4; ++i) \
    DST[i] = *(const bf16x8*)&L[(BB_) + rA1 + i * 128]; }
#define LDBP(DST, BB_) { _Pragma("unroll") for (int j = 0; j < 4; ++j) \
    DST[j] = *(const bf16x8*)&L[(BB_) + 8192 + rB + j * 128]; }
#define MM0(BF) { _Pragma("unroll") for (int i = 0; i < 4; ++i) \
    _Pragma("unroll") for (int j = 0; j < 4; ++j) \
        acc[i][j] = __builtin_amdgcn_mfma_f32_16x16x32_bf16(aF0[i], BF[j], acc[i][j], 0, 0, 0); }
#define MM4(BF) { _Pragma("unroll") for (int i = 0; i < 4; ++i) \
    _Pragma("unroll") for (int j = 0; j < 4; ++j) \
        acc[i + 4][j] = __builtin_amdgcn_mfma_f32_16x16x32_bf16(aF1[i], BF[j], acc[i + 4][j], 0, 0, 0); }

#define ITER(T_, BC, BN_) { \
    const int t_ = (T_); \
    const bool st3 = (t_ + 3) < nk, st2 = (t_ + 2) < nk; \
    const int tn = (t_ + 1 < nk) ? t_ + 1 : nk - 1; \
    const int cb = (t_ & 3) * BUF, nb = (tn & 3) * BUF; \
    /* phase A: stage + aG read + counted publish of tile t+1 */ \
    if (st3) STAGE(t_ + 3); \
    LDAG(aF1, cb); \
    if (st3) { VM8; } else if (st2) { VM4; } else { VM0; } \
    SBAR(); \
    __builtin_amdgcn_s_setprio(1); MM0(bF##BC); __builtin_amdgcn_s_setprio(0); \
    SBAR(); \
    /* phase B: prefetch tile t+1 frags (residency guaranteed), rows 4-7 MFMA */ \
    LDAP(aF0, nb); LDBP(bF##BN_, nb); \
    SBAR(); \
    __builtin_amdgcn_s_setprio(1); MM4(bF##BC); __builtin_amdgcn_s_setprio(0); \
    SBAR(); SCHED0(); }

    // prologue: tiles 0,1,2 staged; tile0 published; preload tile0 frags (one-time lgkm)
    STAGE(0); STAGE(1); STAGE(2);
    VM8; SBAR();
    LDAP(aF0, 0); LDBP(bF0, 0);

    for (int t2 = 0; t2 < nk; t2 += 2) {
        ITER(t2 + 0, 0, 1);
        ITER(t2 + 1, 1, 0);
    }
#undef ITER
#undef STAGE
#undef LDAP
#undef LDAG
#undef LDBP
#undef MM0
#undef MM4

    // epilogue: gates [4][M][2048], sigmoid on g=1,2; C/D map col=lane&15, row=(lane>>4)*4+reg
    const size_t GM2 = (size_t)M << 11;
    #pragma unroll
    for (int i = 0; i < 8; ++i) {
        int r0 = m0 + wr * 128 + i * 16 + kq * 4;
        #pragma unroll
        for (int j = 0; j < 4; ++j) {
            int gc = n0 + wc * 64 + j * 16 + lr;
            float bv = bias[gc];
            int g = gc >> 11;
            bool sig = (g == 1 || g == 2);
            size_t base = (size_t)g * GM2 + (size_t)(gc & 2047);
            #pragma unroll
            for (int q = 0; q < 4; ++q) {
                float v = acc[i][j][q] + bv;
                if (sig) v = 1.f / (1.f + __expf(-v));
                outG[base + (size_t)(r0 + q) * 2048] = f2bf(v);
            }
        }
    }
}

// ============ projection GEMM: BM=128, BN=256, 8 waves (wave tile 64x64) ============
__global__ __launch_bounds__(512, 2) void k_gemm4(
    const u16* __restrict__ A, const u16* __restrict__ BT,
    const float* __restrict__ bias, u16* __restrict__ outC,
    int M, int NB, int K)
{
    constexpr int BM = 128;
    constexpr int BUF = BM * 32 + 8192;
    __shared__ __align__(16) u16 L[4 * BUF];

    const int tid = threadIdx.x;
    const int w = tid >> 6, lane = tid & 63;
    const int wr = w >> 2, wc = w & 3;
    const int lr = lane & 15, kq = lane >> 4;
    const int gx = gridDim.x;
    const int nwg = gx * gridDim.y;
    const int flat = blockIdx.y * gx + blockIdx.x;
    const int swz = (flat & 7) * (nwg >> 3) + (flat >> 3);
    const int m0 = (swz / gx) * BM, n0 = (swz % gx) * 256;
    const int nk = K >> 5;

    const u16* aSrc1; int aDst1;
    {
        int q = tid >> 7, row = tid & 127;
        aSrc1 = A + ((size_t)q * M + m0 + row) * 8;
        aDst1 = (w * 64) * 8;
    }
    const u16* bSrc[2]; int bDst[2];
    #pragma unroll
    for (int l = 0; l < 2; ++l) {
        int tc = tid + l * 512;
        bSrc[l] = BT + ((size_t)(tc >> 8) * NB + n0 + (tc & 255)) * 8;
        bDst[l] = BM * 32 + (w * 64 + l * 512) * 8;
    }
    const size_t aStep = (size_t)32 * M;
    const size_t bStep = (size_t)32 * NB;
    const int rdA = wr * 64 + lr;
    const int rdB = wc * 64 + lr;

    f32x4 acc[4][4] = {};
    bf16x8 aP0[4], bP0[4], aP1[4], bP1[4];

    #pragma unroll
    for (int p = 0; p < 3; ++p) {
        GLL16(aSrc1 + (size_t)p * aStep, &L[p * BUF + aDst1]);
        #pragma unroll
        for (int l = 0; l < 2; ++l) GLL16(bSrc[l] + (size_t)p * bStep, &L[p * BUF + bDst[l]]);
    }
    VM3;
    SBAR(); SCHED0();
    #pragma unroll
    for (int i = 0; i < 4; ++i) aP0[i] = *(const bf16x8*)&L[(kq * BM + rdA + i * 16) * 8];
    #pragma unroll
    for (int j = 0; j < 4; ++j) bP0[j] = *(const bf16x8*)&L[BM * 32 + (kq * 256 + rdB + j * 16) * 8];

#define ITER4(KT, CUR, NXT) { \
    const int kt_ = (KT); \
    const int tn = (kt_ + 1 < nk) ? kt_ + 1 : nk - 1; \
    const int nb = (tn & 3) * BUF; \
    if (kt_ + 3 < nk) { \
        const size_t sa = (size_t)(kt_ + 3) * aStep, sb_ = (size_t)(kt_ + 3) * bStep; \
        const int wb = ((kt_ + 3) & 3) * BUF; \
        GLL16(aSrc1 + sa, &L[wb + aDst1]); \
        _Pragma("unroll") for (int l = 0; l < 2; ++l) GLL16(bSrc[l] + sb_, &L[wb + bDst[l]]); \
    } \
    __builtin_amdgcn_s_setprio(1); \
    _Pragma("unroll") for (int i = 0; i < 4; ++i) \
        _Pragma("unroll") for (int j = 0; j < 4; ++j) \
            acc[i][j] = __builtin_amdgcn_mfma_f32_16x16x32_bf16(aP##CUR[i], bP##CUR[j], acc[i][j], 0, 0, 0); \
    _Pragma("unroll") for (int i = 0; i < 4; ++i) \
        aP##NXT[i] = *(const bf16x8*)&L[nb + (kq * BM + rdA + i * 16) * 8]; \
    _Pragma("unroll") for (int j = 0; j < 4; ++j) \
        bP##NXT[j] = *(const bf16x8*)&L[nb + BM * 32 + (kq * 256 + rdB + j * 16) * 8]; \
    __builtin_amdgcn_s_setprio(0); \
    if (kt_ + 3 < nk) { VM3; } else { VM0; } \
    SBAR(); SCHED0(); }

    for (int kt4 = 0; kt4 < nk; kt4 += 4) {
        ITER4(kt4 + 0, 0, 1);
        ITER4(kt4 + 1, 1, 0);
        ITER4(kt4 + 2, 0, 1);
        ITER4(kt4 + 3, 1, 0);
    }
#undef ITER4

    // epilogue: chunked x2 out: ((gc>>3)*M + r)*8 + (gc&7)
    #pragma unroll
    for (int i = 0; i < 4; ++i) {
        int r0 = m0 + wr * 64 + i * 16 + kq * 4;
        #pragma unroll
        for (int j = 0; j < 4; ++j) {
            int gc = n0 + wc * 64 + j * 16 + lr;
            float bv = bias[gc];
            size_t base = ((size_t)(gc >> 3) * M) * 8 + (size_t)(gc & 7);
            #pragma unroll
            for (int q = 0; q < 4; ++q)
                outC[base + (size_t)(r0 + q) * 8] = f2bf(acc[i][j][q] + bv);
        }
    }
}

// ---- SRU recurrence: one thread per (b,n) chain; hb (if set) written CHUNKED ----
__global__ void k_scan(const u16* __restrict__ G, const float* __restrict__ c0,
                       u16* __restrict__ hb, float* __restrict__ hf,
                       float* __restrict__ cout)
{
    int idx = blockIdx.x * 256 + threadIdx.x;
    int b = idx >> 11, n = idx & 2047;
    float c = c0[idx];
    const size_t GM = (size_t)MR * 2048;
    const size_t hcBase = ((size_t)(n >> 3) * MR) * 8 + (size_t)(n & 7);
    for (int t = 0; t < TT; ++t) {
        int m = t * BB + b;
        size_t p = ((size_t)m << 11) + (size_t)n;
        float xp = bf2f(G[p]);
        float f  = bf2f(G[GM + p]);
        float r  = bf2f(G[2 * GM + p]);
        float cx = bf2f(G[3 * GM + p]);
        c = f * c + (1.f - f) * xp;
        float h = r * tanhf(c) + (1.f - r) * cx;
        if (hb) hb[hcBase + (size_t)m * 8] = f2bf(h);
        if (hf) hf[p] = h;
    }
    if (cout) cout[idx] = c;
}

extern "C" void kernel_launch(void* const* d_in, const int* in_sizes, int n_in,
                              void* d_out, int out_size, void* d_ws, size_t ws_size,
                              hipStream_t stream)
{
    const float* xt  = (const float*)d_in[0];
    const float* ctf = (const float*)d_in[1];
    const float* Wx  = (const float*)d_in[2];
    const float* Wf  = (const float*)d_in[3];
    const float* bfp = (const float*)d_in[4];
    const float* Wr  = (const float*)d_in[5];
    const float* brp = (const float*)d_in[6];
    const float* Wcx = (const float*)d_in[7];
    const float* bcx = (const float*)d_in[8];
    const float* Wcl = (const float*)d_in[9];
    const float* bcl = (const float*)d_in[10];
    float* out = (float*)d_out;

    char* ws = (char*)d_ws;
    u16* x0 = (u16*)ws;       ws += (size_t)MR * NIN * 2;        // chunked
    u16* x2 = (u16*)ws;       ws += (size_t)MR * NIN * 2;        // chunked
    u16* h1 = (u16*)ws;       ws += (size_t)MR * NOUT * 2;       // chunked
    u16* WTall = (u16*)ws;    ws += (size_t)4 * NOUT * NIN * 2;  // chunked
    u16* WclT = (u16*)ws;     ws += (size_t)NIN * NOUT * 2;      // chunked
    float* ball = (float*)ws; ws += (size_t)4 * NOUT * 4;
    u16* G = (u16*)ws;        ws += (size_t)4 * MR * NOUT * 2;   // [4][8192][2048]

    k_cvt_chunk<<<dim3(MR / 64, NIN / 32), 256, 0, stream>>>(xt, x0, MR, NIN);
    k_wT_chunk<<<dim3(NOUT / 64, NIN / 32), 256, 0, stream>>>(Wx,  WTall, NIN, NOUT, 4 * NOUT, 0 * NOUT);
    k_wT_chunk<<<dim3(NOUT / 64, NIN / 32), 256, 0, stream>>>(Wf,  WTall, NIN, NOUT, 4 * NOUT, 1 * NOUT);
    k_wT_chunk<<<dim3(NOUT / 64, NIN / 32), 256, 0, stream>>>(Wr,  WTall, NIN, NOUT, 4 * NOUT, 2 * NOUT);
    k_wT_chunk<<<dim3(NOUT / 64, NIN / 32), 256, 0, stream>>>(Wcx, WTall, NIN, NOUT, 4 * NOUT, 3 * NOUT);
    k_wT_chunk<<<dim3(NIN / 64, NOUT / 32), 256, 0, stream>>>(Wcl, WclT, NOUT, NIN, NIN, 0);
    k_bias_pack<<<32, 256, 0, stream>>>(bfp, brp, bcx, ball);

    // layer 1: fused 4-gate GEMM (NB = 8192, K=1024) + scan (h1 chunked)
    k_gemm8<<<dim3(32, 32), 512, 0, stream>>>(x0, WTall, ball, G, MR, 4 * NOUT, NIN);
    k_scan<<<(BB * NOUT) / 256, 256, 0, stream>>>(G, ctf, h1, (float*)nullptr, (float*)nullptr);

    // inter-layer projection: x2 = h1 @ Wcl + bcl  (grid 4 x 64 = 256)
    k_gemm4<<<dim3(NIN / 256, MR / 128), 512, 0, stream>>>(h1, WclT, bcl, x2, MR, NIN, NOUT);

    // layer 2: gates + scan -> d_out (h2 f32 + c_last)
    k_gemm8<<<dim3(32, 32), 512, 0, stream>>>(x2, WTall, ball, G, MR, 4 * NOUT, NIN);
    k_scan<<<(BB * NOUT) / 256, 256, 0, stream>>>(G, ctf + (size_t)BB * NOUT, (u16*)nullptr, out, out + (size_t)MR * NOUT);
}

// Round 7
// 471.802 us; speedup vs baseline: 1.0681x; 1.0681x over previous
//
#include <hip/hip_runtime.h>

#define TT 128
#define BB 64
#define NIN 1024
#define NOUT 2048
#define MR (TT*BB)   // 8192 rows (T*B)

typedef unsigned short u16;
typedef __attribute__((ext_vector_type(8))) __bf16 bf16x8;
typedef __attribute__((ext_vector_type(4))) float f32x4;
typedef __attribute__((ext_vector_type(8))) unsigned short u16x8;

static __device__ __forceinline__ u16 f2bf(float f) {
    union { float f; unsigned u; } v; v.f = f;
    unsigned r = v.u + 0x7fffu + ((v.u >> 16) & 1u);  // RNE
    return (u16)(r >> 16);
}
static __device__ __forceinline__ float bf2f(u16 x) {
    union { unsigned u; float f; } v; v.u = ((unsigned)x) << 16;
    return v.f;
}

// ---- x [M][K] f32 -> chunked bf16 [(K/8)][M][8] ----
__global__ void k_cvt_chunk(const float* __restrict__ s, u16* __restrict__ d, int M_, int K_) {
    __shared__ float t[64][33];
    int m0 = blockIdx.x * 64, k0 = blockIdx.y * 32;
    int ml = threadIdx.x >> 3, kl = (threadIdx.x & 7) * 4;
    #pragma unroll
    for (int p = 0; p < 2; ++p) {
        float4 v = *(const float4*)&s[(size_t)(m0 + ml + p * 32) * K_ + k0 + kl];
        t[ml + p * 32][kl] = v.x; t[ml + p * 32][kl + 1] = v.y;
        t[ml + p * 32][kl + 2] = v.z; t[ml + p * 32][kl + 3] = v.w;
    }
    __syncthreads();
    int q = threadIdx.x >> 6, row = threadIdx.x & 63;
    u16x8 o;
    #pragma unroll
    for (int j = 0; j < 8; ++j) o[j] = f2bf(t[row][q * 8 + j]);
    *(u16x8*)&d[(((size_t)(k0 >> 3) + q) * M_ + m0 + row) * 8] = o;
}

// ---- W [K][N] f32 -> chunked bf16 B^T [(K/8)][OUTM][8] at row offset ----
__global__ void k_wT_chunk(const float* __restrict__ s, u16* __restrict__ d,
                           int K_, int N_, int OUTM, int row_off) {
    __shared__ float t[32][65];
    int k0 = blockIdx.y * 32, n0 = blockIdx.x * 64;
    int kl = threadIdx.x >> 6, nl = threadIdx.x & 63;
    #pragma unroll
    for (int p = 0; p < 8; ++p)
        t[kl + p * 4][nl] = s[(size_t)(k0 + kl + p * 4) * N_ + n0 + nl];
    __syncthreads();
    int q = threadIdx.x >> 6, row = threadIdx.x & 63;
    u16x8 o;
    #pragma unroll
    for (int j = 0; j < 8; ++j) o[j] = f2bf(t[q * 8 + j][row]);
    *(u16x8*)&d[(((size_t)(k0 >> 3) + q) * OUTM + row_off + n0 + row) * 8] = o;
}

__global__ void k_bias_pack(const float* __restrict__ bf_, const float* __restrict__ br_,
                            const float* __restrict__ bcx_, float* __restrict__ ball) {
    int i = blockIdx.x * 256 + threadIdx.x;
    int g = i >> 11, n = i & 2047;
    float v = 0.f;
    if (g == 1) v = bf_[n];
    else if (g == 2) v = br_[n];
    else if (g == 3) v = bcx_[n];
    ball[i] = v;
}

#define GLL16(SRC, DST) __builtin_amdgcn_global_load_lds( \
    (const __attribute__((address_space(1))) void*)(SRC), \
    (__attribute__((address_space(3))) void*)(DST), 16, 0, 0)
#define SBAR() __builtin_amdgcn_s_barrier()
#define SCHED0() __builtin_amdgcn_sched_barrier(0)
#define VM3 asm volatile("s_waitcnt vmcnt(3)" ::: "memory")
#define VM0 asm volatile("s_waitcnt vmcnt(0)" ::: "memory")

// ============ gate GEMM: BM=BN=256, BK=32, 8 waves, 4-deep ring ============
// R4 free-running ping-pong pipeline, but ONE {vmcnt(0)+barrier} per 2 K-tiles:
// window W computes {t, t+1}, stages {t+2, t+3} (overwriting slots last read in
// window W-1 -> boundary barrier covers the hazard; vmcnt(0) issue-to-wait
// distance is a full window >> HBM latency, so the drain is free).
__global__ __launch_bounds__(512) void k_gemm8(
    const u16* __restrict__ A, const u16* __restrict__ BT,
    const float* __restrict__ bias, u16* __restrict__ outG,
    int M, int NB, int K)
{
    constexpr int BUF = 16384;               // elems per ring slot: A 8192 | B 8192
    __shared__ __align__(16) u16 L[4 * BUF]; // 128 KiB

    const int tid = threadIdx.x;
    const int w = tid >> 6, lane = tid & 63;
    const int wr = w >> 2, wc = w & 3;
    const int lr = lane & 15, kq = lane >> 4;
    // XCD column-band swizzle: xcd owns 4 contiguous n-tiles (2MB B slice, L2-fit)
    const int flat = blockIdx.y * gridDim.x + blockIdx.x;
    const int xcd = flat & 7, bi = flat >> 3;
    const int n0 = (xcd * 4 + (bi & 3)) * 256;
    const int m0 = (bi >> 2) * 256;
    const int nk = K >> 5;                   // BK = 32 (nk even)

    const int t1 = tid + 512;
    const u16* aS0 = A + ((size_t)(tid >> 8) * M + m0 + (tid & 255)) * 8;
    const u16* aS1 = A + ((size_t)(t1 >> 8) * M + m0 + (t1 & 255)) * 8;
    const u16* bS0 = BT + ((size_t)(tid >> 8) * NB + n0 + (tid & 255)) * 8;
    const u16* bS1 = BT + ((size_t)(t1 >> 8) * NB + n0 + (t1 & 255)) * 8;
    const int aD0 = (w * 64) * 8, aD1 = (512 + w * 64) * 8;
    const int bD0 = 8192 + aD0, bD1 = 8192 + aD1;
    const size_t aStep = (size_t)32 * M, bStep = (size_t)32 * NB;

    const int rA0 = (kq * 256 + wr * 128 + lr) * 8;        // rows 0-63 of wave tile
    const int rA1 = (kq * 256 + wr * 128 + 64 + lr) * 8;   // rows 64-127
    const int rB  = (kq * 256 + wc * 64 + lr) * 8;

    f32x4 acc[8][4] = {};
    bf16x8 aP0[4], bP0[4], aP1[4], bP1[4];

#define STAGE(TAU) { const size_t _oA = (size_t)(TAU) * aStep, _oB = (size_t)(TAU) * bStep; \
    const int _wb = ((TAU) & 3) * BUF; \
    GLL16(aS0 + _oA, &L[_wb + aD0]); GLL16(aS1 + _oA, &L[_wb + aD1]); \
    GLL16(bS0 + _oB, &L[_wb + bD0]); GLL16(bS1 + _oB, &L[_wb + bD1]); }
#define LDAP(DST, BB_) { _Pragma("unroll") for (int i = 0; i < 4; ++i) \
    DST[i] = *(const bf16x8*)&L[(BB_) + rA0 + i * 128]; }
#define LDAG(DST, BB_) { _Pragma("unroll") for (int i = 0; i < 4; ++i) \
    DST[i] = *(const bf16x8*)&L[(BB_) + rA1 + i * 128]; }
#define LDBP(DST, BB_) { _Pragma("unroll") for (int j = 0; j < 4; ++j) \
    DST[j] = *(const bf16x8*)&L[(BB_) + 8192 + rB + j * 128]; }
#define MML(AF, BF) { _Pragma("unroll") for (int i = 0; i < 4; ++i) \
    _Pragma("unroll") for (int j = 0; j < 4; ++j) \
        acc[i][j] = __builtin_amdgcn_mfma_f32_16x16x32_bf16(AF[i], BF[j], acc[i][j], 0, 0, 0); }
#define MMU(AF, BF) { _Pragma("unroll") for (int i = 0; i < 4; ++i) \
    _Pragma("unroll") for (int j = 0; j < 4; ++j) \
        acc[i + 4][j] = __builtin_amdgcn_mfma_f32_16x16x32_bf16(AF[i], BF[j], acc[i + 4][j], 0, 0, 0); }

    // prologue: stage tiles 0,1; publish; preload tile0 lower frags
    STAGE(0); STAGE(1);
    VM0; SBAR(); SCHED0();
    LDAP(aP0, 0); LDBP(bP0, 0);

    for (int t = 0; t < nk; t += 2) {
        const int cb = (t & 3) * BUF;
        const int nb = ((t + 1) & 3) * BUF;
        const bool s2 = (t + 2) < nk, s3 = (t + 3) < nk;
        // ---- tile t ----
        {
            bf16x8 aG[4];
            LDAG(aG, cb);
            if (s2) STAGE(t + 2);
            __builtin_amdgcn_s_setprio(1);
            MML(aP0, bP0);
            __builtin_amdgcn_s_setprio(0);
            LDAP(aP1, nb); LDBP(bP1, nb);        // frags(t+1): staged W-1, published
            __builtin_amdgcn_s_setprio(1);
            MMU(aG, bP0);
            __builtin_amdgcn_s_setprio(0);
        }
        // ---- tile t+1 ----
        {
            bf16x8 aG[4];
            LDAG(aG, nb);
            if (s3) STAGE(t + 3);
            __builtin_amdgcn_s_setprio(1);
            MML(aP1, bP1);
            MMU(aG, bP1);
            __builtin_amdgcn_s_setprio(0);
        }
        // ---- window boundary: publish {t+2, t+3} ----
        VM0; SBAR(); SCHED0();
        if (s2) { LDAP(aP0, ((t + 2) & 3) * BUF); LDBP(bP0, ((t + 2) & 3) * BUF); }
    }
#undef STAGE
#undef LDAP
#undef LDAG
#undef LDBP
#undef MML
#undef MMU

    // epilogue: gates [4][M][2048], sigmoid on g=1,2; C/D map col=lane&15, row=(lane>>4)*4+reg
    const size_t GM2 = (size_t)M << 11;
    #pragma unroll
    for (int i = 0; i < 8; ++i) {
        int r0 = m0 + wr * 128 + i * 16 + kq * 4;
        #pragma unroll
        for (int j = 0; j < 4; ++j) {
            int gc = n0 + wc * 64 + j * 16 + lr;
            float bv = bias[gc];
            int g = gc >> 11;
            bool sig = (g == 1 || g == 2);
            size_t base = (size_t)g * GM2 + (size_t)(gc & 2047);
            #pragma unroll
            for (int q = 0; q < 4; ++q) {
                float v = acc[i][j][q] + bv;
                if (sig) v = 1.f / (1.f + __expf(-v));
                outG[base + (size_t)(r0 + q) * 2048] = f2bf(v);
            }
        }
    }
}

// ============ projection GEMM: BM=128, BN=256, 8 waves (wave tile 64x64) ============
__global__ __launch_bounds__(512, 2) void k_gemm4(
    const u16* __restrict__ A, const u16* __restrict__ BT,
    const float* __restrict__ bias, u16* __restrict__ outC,
    int M, int NB, int K)
{
    constexpr int BM = 128;
    constexpr int BUF = BM * 32 + 8192;
    __shared__ __align__(16) u16 L[4 * BUF];

    const int tid = threadIdx.x;
    const int w = tid >> 6, lane = tid & 63;
    const int wr = w >> 2, wc = w & 3;
    const int lr = lane & 15, kq = lane >> 4;
    const int gx = gridDim.x;
    const int nwg = gx * gridDim.y;
    const int flat = blockIdx.y * gx + blockIdx.x;
    const int swz = (flat & 7) * (nwg >> 3) + (flat >> 3);
    const int m0 = (swz / gx) * BM, n0 = (swz % gx) * 256;
    const int nk = K >> 5;

    const u16* aSrc1; int aDst1;
    {
        int q = tid >> 7, row = tid & 127;
        aSrc1 = A + ((size_t)q * M + m0 + row) * 8;
        aDst1 = (w * 64) * 8;
    }
    const u16* bSrc[2]; int bDst[2];
    #pragma unroll
    for (int l = 0; l < 2; ++l) {
        int tc = tid + l * 512;
        bSrc[l] = BT + ((size_t)(tc >> 8) * NB + n0 + (tc & 255)) * 8;
        bDst[l] = BM * 32 + (w * 64 + l * 512) * 8;
    }
    const size_t aStep = (size_t)32 * M;
    const size_t bStep = (size_t)32 * NB;
    const int rdA = wr * 64 + lr;
    const int rdB = wc * 64 + lr;

    f32x4 acc[4][4] = {};
    bf16x8 aP0[4], bP0[4], aP1[4], bP1[4];

    #pragma unroll
    for (int p = 0; p < 3; ++p) {
        GLL16(aSrc1 + (size_t)p * aStep, &L[p * BUF + aDst1]);
        #pragma unroll
        for (int l = 0; l < 2; ++l) GLL16(bSrc[l] + (size_t)p * bStep, &L[p * BUF + bDst[l]]);
    }
    VM3;
    SBAR(); SCHED0();
    #pragma unroll
    for (int i = 0; i < 4; ++i) aP0[i] = *(const bf16x8*)&L[(kq * BM + rdA + i * 16) * 8];
    #pragma unroll
    for (int j = 0; j < 4; ++j) bP0[j] = *(const bf16x8*)&L[BM * 32 + (kq * 256 + rdB + j * 16) * 8];

#define ITER4(KT, CUR, NXT) { \
    const int kt_ = (KT); \
    const int tn = (kt_ + 1 < nk) ? kt_ + 1 : nk - 1; \
    const int nb = (tn & 3) * BUF; \
    if (kt_ + 3 < nk) { \
        const size_t sa = (size_t)(kt_ + 3) * aStep, sb_ = (size_t)(kt_ + 3) * bStep; \
        const int wb = ((kt_ + 3) & 3) * BUF; \
        GLL16(aSrc1 + sa, &L[wb + aDst1]); \
        _Pragma("unroll") for (int l = 0; l < 2; ++l) GLL16(bSrc[l] + sb_, &L[wb + bDst[l]]); \
    } \
    __builtin_amdgcn_s_setprio(1); \
    _Pragma("unroll") for (int i = 0; i < 4; ++i) \
        _Pragma("unroll") for (int j = 0; j < 4; ++j) \
            acc[i][j] = __builtin_amdgcn_mfma_f32_16x16x32_bf16(aP##CUR[i], bP##CUR[j], acc[i][j], 0, 0, 0); \
    _Pragma("unroll") for (int i = 0; i < 4; ++i) \
        aP##NXT[i] = *(const bf16x8*)&L[nb + (kq * BM + rdA + i * 16) * 8]; \
    _Pragma("unroll") for (int j = 0; j < 4; ++j) \
        bP##NXT[j] = *(const bf16x8*)&L[nb + BM * 32 + (kq * 256 + rdB + j * 16) * 8]; \
    __builtin_amdgcn_s_setprio(0); \
    if (kt_ + 3 < nk) { VM3; } else { VM0; } \
    SBAR(); SCHED0(); }

    for (int kt4 = 0; kt4 < nk; kt4 += 4) {
        ITER4(kt4 + 0, 0, 1);
        ITER4(kt4 + 1, 1, 0);
        ITER4(kt4 + 2, 0, 1);
        ITER4(kt4 + 3, 1, 0);
    }
#undef ITER4

    // epilogue: chunked x2 out: ((gc>>3)*M + r)*8 + (gc&7)
    #pragma unroll
    for (int i = 0; i < 4; ++i) {
        int r0 = m0 + wr * 64 + i * 16 + kq * 4;
        #pragma unroll
        for (int j = 0; j < 4; ++j) {
            int gc = n0 + wc * 64 + j * 16 + lr;
            float bv = bias[gc];
            size_t base = ((size_t)(gc >> 3) * M) * 8 + (size_t)(gc & 7);
            #pragma unroll
            for (int q = 0; q < 4; ++q)
                outC[base + (size_t)(r0 + q) * 8] = f2bf(acc[i][j][q] + bv);
        }
    }
}

// ---- SRU recurrence: one thread per (b,n) chain; hb (if set) written CHUNKED ----
__global__ void k_scan(const u16* __restrict__ G, const float* __restrict__ c0,
                       u16* __restrict__ hb, float* __restrict__ hf,
                       float* __restrict__ cout)
{
    int idx = blockIdx.x * 256 + threadIdx.x;
    int b = idx >> 11, n = idx & 2047;
    float c = c0[idx];
    const size_t GM = (size_t)MR * 2048;
    const size_t hcBase = ((size_t)(n >> 3) * MR) * 8 + (size_t)(n & 7);
    for (int t = 0; t < TT; ++t) {
        int m = t * BB + b;
        size_t p = ((size_t)m << 11) + (size_t)n;
        float xp = bf2f(G[p]);
        float f  = bf2f(G[GM + p]);
        float r  = bf2f(G[2 * GM + p]);
        float cx = bf2f(G[3 * GM + p]);
        c = f * c + (1.f - f) * xp;
        float h = r * tanhf(c) + (1.f - r) * cx;
        if (hb) hb[hcBase + (size_t)m * 8] = f2bf(h);
        if (hf) hf[p] = h;
    }
    if (cout) cout[idx] = c;
}

extern "C" void kernel_launch(void* const* d_in, const int* in_sizes, int n_in,
                              void* d_out, int out_size, void* d_ws, size_t ws_size,
                              hipStream_t stream)
{
    const float* xt  = (const float*)d_in[0];
    const float* ctf = (const float*)d_in[1];
    const float* Wx  = (const float*)d_in[2];
    const float* Wf  = (const float*)d_in[3];
    const float* bfp = (const float*)d_in[4];
    const float* Wr  = (const float*)d_in[5];
    const float* brp = (const float*)d_in[6];
    const float* Wcx = (const float*)d_in[7];
    const float* bcx = (const float*)d_in[8];
    const float* Wcl = (const float*)d_in[9];
    const float* bcl = (const float*)d_in[10];
    float* out = (float*)d_out;

    char* ws = (char*)d_ws;
    u16* x0 = (u16*)ws;       ws += (size_t)MR * NIN * 2;        // chunked
    u16* x2 = (u16*)ws;       ws += (size_t)MR * NIN * 2;        // chunked
    u16* h1 = (u16*)ws;       ws += (size_t)MR * NOUT * 2;       // chunked
    u16* WTall = (u16*)ws;    ws += (size_t)4 * NOUT * NIN * 2;  // chunked
    u16* WclT = (u16*)ws;     ws += (size_t)NIN * NOUT * 2;      // chunked
    float* ball = (float*)ws; ws += (size_t)4 * NOUT * 4;
    u16* G = (u16*)ws;        ws += (size_t)4 * MR * NOUT * 2;   // [4][8192][2048]

    k_cvt_chunk<<<dim3(MR / 64, NIN / 32), 256, 0, stream>>>(xt, x0, MR, NIN);
    k_wT_chunk<<<dim3(NOUT / 64, NIN / 32), 256, 0, stream>>>(Wx,  WTall, NIN, NOUT, 4 * NOUT, 0 * NOUT);
    k_wT_chunk<<<dim3(NOUT / 64, NIN / 32), 256, 0, stream>>>(Wf,  WTall, NIN, NOUT, 4 * NOUT, 1 * NOUT);
    k_wT_chunk<<<dim3(NOUT / 64, NIN / 32), 256, 0, stream>>>(Wr,  WTall, NIN, NOUT, 4 * NOUT, 2 * NOUT);
    k_wT_chunk<<<dim3(NOUT / 64, NIN / 32), 256, 0, stream>>>(Wcx, WTall, NIN, NOUT, 4 * NOUT, 3 * NOUT);
    k_wT_chunk<<<dim3(NIN / 64, NOUT / 32), 256, 0, stream>>>(Wcl, WclT, NOUT, NIN, NIN, 0);
    k_bias_pack<<<32, 256, 0, stream>>>(bfp, brp, bcx, ball);

    // layer 1: fused 4-gate GEMM (NB = 8192, K=1024) + scan (h1 chunked)
    k_gemm8<<<dim3(32, 32), 512, 0, stream>>>(x0, WTall, ball, G, MR, 4 * NOUT, NIN);
    k_scan<<<(BB * NOUT) / 256, 256, 0, stream>>>(G, ctf, h1, (float*)nullptr, (float*)nullptr);

    // inter-layer projection: x2 = h1 @ Wcl + bcl  (grid 4 x 64 = 256)
    k_gemm4<<<dim3(NIN / 256, MR / 128), 512, 0, stream>>>(h1, WclT, bcl, x2, MR, NIN, NOUT);

    // layer 2: gates + scan -> d_out (h2 f32 + c_last)
    k_gemm8<<<dim3(32, 32), 512, 0, stream>>>(x2, WTall, ball, G, MR, 4 * NOUT, NIN);
    k_scan<<<(BB * NOUT) / 256, 256, 0, stream>>>(G, ctf + (size_t)BB * NOUT, (u16*)nullptr, out, out + (size_t)MR * NOUT);
}